// Round 10
// baseline (76.907 us; speedup 1.0000x reference)
//
#include <hip/hip_runtime.h>

#define DM    1024
#define NTOK  32768   // B*S
#define NRED  16384
#define NSAVE 16384
#define MMAX  16384   // max compacted rows

typedef __attribute__((ext_vector_type(8))) short bf16x8;
typedef __attribute__((ext_vector_type(4))) float f32x4;

__device__ __forceinline__ ushort f2bf(float f) {
    union { float f; unsigned u; } v; v.f = f;
    unsigned r = (v.u + 0x7FFF + ((v.u >> 16) & 1)) >> 16;   // RNE
    return (ushort)r;
}
__device__ __forceinline__ float bf2f(ushort u) {
    union { unsigned u; float f; } v; v.u = ((unsigned)u) << 16;
    return v.f;
}

// ---------------------------------------------------------------------------
__global__ __launch_bounds__(256) void setup_kernel(const float* __restrict__ W,
                                                    ushort* __restrict__ Wb,
                                                    int* __restrict__ cnt,
                                                    int* __restrict__ need,
                                                    int* __restrict__ counter) {
    int t = blockIdx.x * 256 + threadIdx.x;
    float4 v = ((const float4*)W)[t];
    ushort4 o;
    o.x = f2bf(v.x); o.y = f2bf(v.y); o.z = f2bf(v.z); o.w = f2bf(v.w);
    ((ushort4*)Wb)[t] = o;
    if (t < NTOK) { cnt[t] = 0; need[t] = 0; }
    if (t == 0) *counter = 0;
}

// ---------------------------------------------------------------------------
__global__ __launch_bounds__(256) void prep_kernel(const int* __restrict__ red,
                                                   const int* __restrict__ sav,
                                                   int* __restrict__ cnt,
                                                   int* __restrict__ need) {
    int j = blockIdx.x * 256 + threadIdx.x;
    if (j >= NRED) return;
    atomicAdd(&cnt[red[j]], 1);
    int s = sav[j];
    if (s > 0) need[s - 1] = 1;
}

// ---------------------------------------------------------------------------
__global__ __launch_bounds__(256) void compact_kernel(const int* __restrict__ cnt,
                                                      const int* __restrict__ need,
                                                      int* __restrict__ inv,
                                                      int* __restrict__ list,
                                                      int* __restrict__ counter) {
    int t = blockIdx.x * 256 + threadIdx.x;
    if (t >= NTOK) return;
    if (need[t] && cnt[t] > 0) {
        int pos = atomicAdd(counter, 1);
        inv[t] = pos;
        list[pos] = t;
    }
}

// ---------------------------------------------------------------------------
// convx: gather + fp32->bf16 convert compacted rows; zero-pad to 128 multiple
// ---------------------------------------------------------------------------
__global__ __launch_bounds__(256) void convx_kernel(const float* __restrict__ X,
                                                    const int* __restrict__ list,
                                                    const int* __restrict__ counter,
                                                    ushort* __restrict__ Xb) {
    const int M = *counter;
    const int Mpad = (M + 127) & ~127;
    for (int r = blockIdx.x; r < Mpad; r += gridDim.x) {
        ushort4 o;
        if (r < M) {
            int src = list[r];
            float4 v = ((const float4*)(X + (size_t)src * DM))[threadIdx.x];
            o.x = f2bf(v.x); o.y = f2bf(v.y); o.z = f2bf(v.z); o.w = f2bf(v.w);
        } else {
            o.x = 0; o.y = 0; o.z = 0; o.w = 0;
        }
        ((ushort4*)(Xb + (size_t)r * DM))[threadIdx.x] = o;
    }
}

// ---------------------------------------------------------------------------
// bf16 MFMA GEMM, depth-2 pipelined: Tb[m,n] = bf16( sum_k Xb[m,k]*Wb[n,k] )
// BM=BN=128, BK=32, 4 waves; wave w owns m-rows [w*32,w*32+32) x all 128 n
// (2x8 frags of 16x16x32, 16 MFMA/step, acc 64 VGPR). THREE 16 KB LDS bufs
// (48 KB -> 3 wg/CU = 12 waves/CU): step t computes buf[t%3], stages
// buf[(t+2)%3], waits vmcnt(8) -> consumed loads were issued TWO compute
// phases ago (depth-2 latency tolerance; R9 post-mortem: latency, not LDS
// pipe, binds this shape). BK=32 rows are 64 B, so each fragment read is a
// contiguous 1 KB wave read -> zero bank conflicts, no swizzle, and staging
// is plain linear global_load_lds(16). setprio(1) around MFMA (T5: 3
// independent wgs/CU = phase-diverse). 2 barriers/step as in R7 (validated).
// ---------------------------------------------------------------------------
__global__ __launch_bounds__(256) void gemm_kernel(const ushort* __restrict__ Xb,
                                                   const ushort* __restrict__ Wb,
                                                   const int* __restrict__ counter,
                                                   ushort* __restrict__ Tb) {
    const int M = *counter;
    const int m0 = blockIdx.x * 128;
    if (m0 >= M) return;                 // uniform exit before any barrier
    const int n0 = blockIdx.y * 128;

    __shared__ char lds[49152];          // 3 bufs x (A 8KB + B 8KB)

    const int tid = threadIdx.x;
    const int l   = tid & 63;
    const int w   = tid >> 6;            // 0..3

    // staging: wave w covers rows [w*32, w*32+32) of A and of B; instr i
    // covers 16 rows; lane: row = w*32 + i*16 + (l>>2), 16B chunk c = l&3.
    const int srow = l >> 2;             // 0..15
    const int sc   = l & 3;
    const ushort* aS = Xb + (size_t)(m0 + w * 32 + srow) * DM + sc * 8;
    const ushort* bS = Wb + (size_t)(n0 + w * 32 + srow) * DM + sc * 8;
    const int dOff = w * 2048;           // byte offset of wave's 32-row band

#define STAGE(buf, kstep) do {                                                        \
    char* _d = lds + (buf) * 16384 + dOff;                                            \
    const int _k = (kstep) * 32;                                                      \
    __builtin_amdgcn_global_load_lds(                                                 \
        (const __attribute__((address_space(1))) unsigned*)(aS + _k),                 \
        (__attribute__((address_space(3))) unsigned*)(_d), 16, 0, 0);                 \
    __builtin_amdgcn_global_load_lds(                                                 \
        (const __attribute__((address_space(1))) unsigned*)(aS + _k + 16 * DM),       \
        (__attribute__((address_space(3))) unsigned*)(_d + 1024), 16, 0, 0);          \
    __builtin_amdgcn_global_load_lds(                                                 \
        (const __attribute__((address_space(1))) unsigned*)(bS + _k),                 \
        (__attribute__((address_space(3))) unsigned*)(_d + 8192), 16, 0, 0);          \
    __builtin_amdgcn_global_load_lds(                                                 \
        (const __attribute__((address_space(1))) unsigned*)(bS + _k + 16 * DM),       \
        (__attribute__((address_space(3))) unsigned*)(_d + 8192 + 1024), 16, 0, 0);   \
} while (0)

    // fragment read byte-offsets within a buffer (LDS rows 64 B, linear)
    const int kgrp = l >> 4;
    const int r16  = l & 15;
    int aoff[2], boff[8];
#pragma unroll
    for (int fm = 0; fm < 2; ++fm)
        aoff[fm] = (w * 32 + fm * 16 + r16) * 64 + kgrp * 16;
#pragma unroll
    for (int fn = 0; fn < 8; ++fn)
        boff[fn] = 8192 + (fn * 16 + r16) * 64 + kgrp * 16;

    f32x4 acc[2][8] = {};

    STAGE(0, 0);
    STAGE(1, 1);
#pragma unroll
    for (int t = 0; t < 32; ++t) {
        const char* base = lds + (t % 3) * 16384;
        if (t < 30) {
            STAGE((t + 2) % 3, t + 2);
            asm volatile("s_waitcnt vmcnt(8)" ::: "memory");   // buf[t%3]'s loads landed (mine)
        } else if (t == 30) {
            asm volatile("s_waitcnt vmcnt(4)" ::: "memory");
        } else {
            asm volatile("s_waitcnt vmcnt(0)" ::: "memory");
        }
        __builtin_amdgcn_sched_barrier(0);
        __builtin_amdgcn_s_barrier();                          // landed for ALL waves

        bf16x8 af[2], bfr[8];
#pragma unroll
        for (int fm = 0; fm < 2; ++fm) af[fm]  = *(const bf16x8*)(base + aoff[fm]);
#pragma unroll
        for (int fn = 0; fn < 8; ++fn) bfr[fn] = *(const bf16x8*)(base + boff[fn]);
        __builtin_amdgcn_s_setprio(1);
#pragma unroll
        for (int fm = 0; fm < 2; ++fm)
#pragma unroll
            for (int fn = 0; fn < 8; ++fn)
                acc[fm][fn] = __builtin_amdgcn_mfma_f32_16x16x32_bf16(af[fm], bfr[fn], acc[fm][fn], 0, 0, 0);
        __builtin_amdgcn_s_setprio(0);

        if (t < 31)
            __builtin_amdgcn_s_barrier();   // all reads of buf[t%3] done; t+1 may overwrite it
    }
#undef STAGE

    // C/D layout: col = lane&15, row = (lane>>4)*4 + reg  [m89]
#pragma unroll
    for (int fm = 0; fm < 2; ++fm) {
        int mbase = m0 + w * 32 + fm * 16 + kgrp * 4;
#pragma unroll
        for (int fn = 0; fn < 8; ++fn) {
            int n = n0 + fn * 16 + r16;
#pragma unroll
            for (int r = 0; r < 4; ++r) {
                int m = mbase + r;
                if (m < M) Tb[(size_t)m * DM + n] = f2bf(acc[fm][fn][r]);
            }
        }
    }
}

// ---------------------------------------------------------------------------
// epilogue: out[r] = x[s] + cnt[s-1] * Tb[inv[s-1]]
// ---------------------------------------------------------------------------
__global__ __launch_bounds__(256) void out_kernel(const float* __restrict__ X,
                                                  const ushort* __restrict__ Tb,
                                                  const int* __restrict__ sav,
                                                  const int* __restrict__ cnt,
                                                  const int* __restrict__ inv,
                                                  float* __restrict__ out) {
    int r = blockIdx.x;
    int d = threadIdx.x;                 // float4 lane, 0..255
    int s = sav[r];
    const float4* xr = (const float4*)(X + (size_t)s * DM);
    float4 v = xr[d];
    if (s > 0) {
        int t = s - 1;
        int c = cnt[t];
        if (c > 0) {
            float fc = (float)c;
            const ushort4* tr = (const ushort4*)(Tb + (size_t)inv[t] * DM);
            ushort4 wv = tr[d];
            v.x += fc * bf2f(wv.x); v.y += fc * bf2f(wv.y);
            v.z += fc * bf2f(wv.z); v.w += fc * bf2f(wv.w);
        }
    }
    ((float4*)out)[(size_t)r * (DM / 4) + d] = v;
}

// ---------------------------------------------------------------------------
extern "C" void kernel_launch(void* const* d_in, const int* in_sizes, int n_in,
                              void* d_out, int out_size, void* d_ws, size_t ws_size,
                              hipStream_t stream) {
    const float* X   = (const float*)d_in[0];
    const float* W   = (const float*)d_in[1];
    const int*   sav = (const int*)d_in[2];   // ids_to_save
    const int*   red = (const int*)d_in[3];   // ids_to_reduce
    float* out = (float*)d_out;

    char* ws = (char*)d_ws;
    int* counter = (int*)ws;                  // 64 ints
    int* cnt  = counter + 64;                 // 32768
    int* need = cnt + NTOK;                   // 32768
    int* inv  = need + NTOK;                  // 32768
    int* list = inv + NTOK;                   // 16384  (ends < 512 KB)
    ushort* Wb = (ushort*)(ws + (1 << 19));   // 2 MB bf16 W
    ushort* Xb = (ushort*)(ws + (4 << 20));   // 32 MB bf16 compacted X rows (padded)
    ushort* Tb = (ushort*)(ws + (36u << 20)); // 32 MB bf16 T

    setup_kernel<<<DM * DM / 4 / 256, 256, 0, stream>>>(W, Wb, cnt, need, counter);
    prep_kernel<<<NRED / 256, 256, 0, stream>>>(red, sav, cnt, need);
    compact_kernel<<<NTOK / 256, 256, 0, stream>>>(cnt, need, inv, list, counter);
    convx_kernel<<<2048, 256, 0, stream>>>(X, list, counter, Xb);

    dim3 ggrid(MMAX / 128, DM / 128);         // x = m-blocks (128, early-exit), y = n (8)
    gemm_kernel<<<ggrid, 256, 0, stream>>>(Xb, Wb, counter, Tb);

    out_kernel<<<NSAVE, 256, 0, stream>>>(X, Tb, sav, cnt, inv, out);
}